// Round 7
// baseline (7802.333 us; speedup 1.0000x reference)
//
#include <hip/hip_runtime.h>

// ResidualSkipRNNForecaster — MI355X register-stationary MFMA RNN,
// XCD-local (L2-shared) exchange with agent-scope fallback.
//
// R6 measured: one blocking cross-block rendezvous per step at ~5us (relaxed
// agent-scope ops carry sc1 -> serviced at the coherent point / IOD; FETCH
// 1.6GB = poll+payload traffic). Fix: groups formed from SAME-XCD blocks
// (HW_REG_XCC_ID, hwreg 20, measured m09) exchange through their shared XCD
// L2: producers publish with PLAIN stores (write-through L1 -> L2), consumers
// read with sc0 loads (bypass own L1, hit shared L2) -> ~200cy instead of
// ~12000cy. Robustness (G16: placement not guaranteed): dynamic grouping via
// atomic per-XCD queues + one-time grid arrive-barrier (all 256 blocks
// co-resident: LDS 60KB => >=2 blocks/CU on 256 CUs); producers DUAL-publish
// (fast L2 copy + sc1 mirror); consumers bounded-spin on the fast flag and
// permanently demote to the mirror on timeout. Wrong XCD info => R6-speed,
// still correct. Structure (phases A/B/C, LN folded, 5 barriers/step)
// unchanged from R6.

#define T_SZ 1024
#define DD   64
#define HH   512
#define NCH  8
#define NBLK 16
#define POLL_TO 4096

typedef __attribute__((ext_vector_type(8))) short short8;
typedef __attribute__((ext_vector_type(4))) float f32x4;
typedef unsigned long long ull;

__device__ __forceinline__ unsigned short f2b(float f) {
  unsigned u = __float_as_uint(f);
  u += 0x7fffu + ((u >> 16) & 1u);   // RNE
  return (unsigned short)(u >> 16);
}
__device__ __forceinline__ float b2f(unsigned short s) {
  return __uint_as_float(((unsigned)s) << 16);
}
__device__ __forceinline__ ull packf2(float a, float b) {
  return (ull)__float_as_uint(a) | ((ull)__float_as_uint(b) << 32);
}
__device__ __forceinline__ float unpack_lo(ull u) { return __uint_as_float((unsigned)u); }
__device__ __forceinline__ float unpack_hi(ull u) { return __uint_as_float((unsigned)(u >> 32)); }

// ---- slow path (coherent point; sc1) ----
__device__ __forceinline__ void st_rlx(ull* p, ull v) {
  __hip_atomic_store(p, v, __ATOMIC_RELAXED, __HIP_MEMORY_SCOPE_AGENT);
}
__device__ __forceinline__ ull ld_rlx(const ull* p) {
  return __hip_atomic_load(p, __ATOMIC_RELAXED, __HIP_MEMORY_SCOPE_AGENT);
}
__device__ __forceinline__ unsigned ld_flag(const unsigned* p) {
  return __hip_atomic_load(p, __ATOMIC_RELAXED, __HIP_MEMORY_SCOPE_AGENT);
}
__device__ __forceinline__ void st_flag(unsigned* p, unsigned v) {
  asm volatile("" ::: "memory");
  __hip_atomic_store(p, v, __ATOMIC_RELAXED, __HIP_MEMORY_SCOPE_AGENT);
}

// ---- fast path (same-XCD shared L2) ----
__device__ __forceinline__ void stp(ull* p, ull v) {        // plain store -> L2
  __hip_atomic_store(p, v, __ATOMIC_RELAXED, __HIP_MEMORY_SCOPE_WORKGROUP);
}
__device__ __forceinline__ void stp32(unsigned* p, unsigned v) {
  asm volatile("" ::: "memory");
  __hip_atomic_store(p, v, __ATOMIC_RELAXED, __HIP_MEMORY_SCOPE_WORKGROUP);
}
__device__ __forceinline__ unsigned ld_l2(const unsigned* p) {   // sc0: skip L1, hit L2
  unsigned v;
  asm volatile("global_load_dword %0, %1, off sc0\n\ts_waitcnt vmcnt(0)"
               : "=v"(v) : "v"(p) : "memory");
  return v;
}
__device__ __forceinline__ ull ld_l2_64(const ull* p) {
  ull v;
  asm volatile("global_load_dwordx2 %0, %1, off sc0\n\ts_waitcnt vmcnt(0)"
               : "=v"(v) : "v"(p) : "memory");
  return v;
}

__global__ void prep_kernel(const float* __restrict__ Wh0, const float* __restrict__ Wi1,
                            const float* __restrict__ Wh1,
                            const float* __restrict__ bi0, const float* __restrict__ bh0,
                            const float* __restrict__ bi1, const float* __restrict__ bh1,
                            const float* __restrict__ g0, const float* __restrict__ be0,
                            const float* __restrict__ g1, const float* __restrict__ be1,
                            float* __restrict__ cvec,
                            unsigned* __restrict__ flagF, unsigned* __restrict__ flagS,
                            unsigned* __restrict__ ctrl) {
  int g = blockIdx.x * blockDim.x + threadIdx.x;
  if (g < HH) {
    float uw0 = 0.f, qw0 = 0.f, uw1 = 0.f, qw1 = 0.f, uh1 = 0.f, qh1 = 0.f;
    for (int j = 0; j < HH; ++j) {
      float a = Wh0[j * HH + g], b = Wi1[j * HH + g], d = Wh1[j * HH + g];
      uw0 += g0[j] * a; qw0 += be0[j] * a;
      uw1 += g0[j] * b; qw1 += be0[j] * b;
      uh1 += g1[j] * d; qh1 += be1[j] * d;
    }
    float b0 = bi0[g] + bh0[g], b1 = bi1[g] + bh1[g];
    cvec[0 * HH + g] = b0 + qw0;
    cvec[1 * HH + g] = b0;
    cvec[2 * HH + g] = b1 + qw1 + qh1;
    cvec[3 * HH + g] = b1 + qw1;
    cvec[4 * HH + g] = uw0;
    cvec[5 * HH + g] = uw1;
    cvec[6 * HH + g] = uh1;
  }
  if (g < 4096) { flagF[g] = 0; flagS[g] = 0; }
  if (g < 32) ctrl[g] = 0;                                  // q[16],arrive,gctr,leftq
  if (g >= 32 && g < 288) ctrl[g] = 0xFFFFFFFFu;            // grp_tab[16][16]
}

__global__ __launch_bounds__(512, 1) void rnn_mfma(
    const float* __restrict__ x,
    const float* __restrict__ Wi0, const float* __restrict__ Wh0,
    const float* __restrict__ Wi1, const float* __restrict__ Wh1,
    const float* __restrict__ cvec,
    const float* __restrict__ g0v, const float* __restrict__ be0v,
    const float* __restrict__ g1v, const float* __restrict__ be1v,
    const float* __restrict__ wfc, const float* __restrict__ bfc,
    ull* __restrict__ payF, ull* __restrict__ payS,
    ull* __restrict__ pstF, ull* __restrict__ pstS,
    unsigned* __restrict__ flagF, unsigned* __restrict__ flagS,
    unsigned* __restrict__ ctrl, float* __restrict__ out) {

  const int tid = threadIdx.x;
  const int wave = tid >> 6, lane = tid & 63;
  const int quad = lane >> 4, m16 = lane & 15;

  __shared__ unsigned short a0bf[16][536];
  __shared__ unsigned short a1bf[16][536];
  __shared__ unsigned short xsb[2][16][72];
  __shared__ float parts[8][8][33];
  __shared__ float partsB[8][8][33];
  __shared__ float partsX[2][8][33];
  __shared__ float2 st0[NCH][NBLK];
  __shared__ float2 st1[NCH][NBLK];
  __shared__ int rdy0s, rdy1s, dems;
  __shared__ int gid_s, p_s, mode_s;
  volatile int* rdy0 = &rdy0s;
  volatile int* rdy1 = &rdy1s;
  volatile int* dem  = &dems;

  // ---------------- dynamic same-XCD grouping ----------------
  unsigned xcc;
  asm volatile("s_getreg_b32 %0, hwreg(20, 0, 32)" : "=s"(xcc));  // HW_REG_XCC_ID
  xcc &= 15u;
  if (tid == 0) {
    rdy0s = 0; rdy1s = 0; dems = 0;
    unsigned slot = atomicAdd(&ctrl[xcc], 1u);
    asm volatile("s_waitcnt vmcnt(0)" ::: "memory");   // q-RMW committed before arrive
    atomicAdd(&ctrl[16], 1u);
    while (ld_flag(&ctrl[16]) < 256u) __builtin_amdgcn_s_sleep(2);
    unsigned F = 0, cnt_my = 0;
    for (int i2 = 0; i2 < 16; ++i2) {
      unsigned c2 = ld_flag(&ctrl[i2]);
      if ((unsigned)i2 == xcc) cnt_my = c2;
      F += c2 >> 4;
    }
    int gid, pp, mode;
    if (slot < (cnt_my >> 4) * 16u) {                  // full same-XCD group
      unsigned seg = slot >> 4;
      pp = (int)(slot & 15u); mode = 1;
      unsigned* tab = &ctrl[32 + xcc * 16 + seg];
      if (pp == 0) {
        gid = (int)atomicAdd(&ctrl[17], 1u);
        st_flag(tab, (unsigned)gid);
      } else {
        unsigned v;
        while ((v = ld_flag(tab)) == 0xFFFFFFFFu) __builtin_amdgcn_s_sleep(2);
        gid = (int)v;
      }
    } else {                                           // leftover -> agent-scope group
      unsigned l = atomicAdd(&ctrl[18], 1u);
      gid = (int)(F + (l >> 4)); pp = (int)(l & 15u); mode = 0;
    }
    gid_s = gid; p_s = pp; mode_s = mode;
  }
  __syncthreads();
  const int gid = gid_s, p = p_s;
  const bool xfast = (mode_s != 0);
  const int gslot = gid * NBLK + p;

  // ---------------- init ----------------
  for (int i = tid; i < 16 * 536; i += 512) {
    (&a0bf[0][0])[i] = 0; (&a1bf[0][0])[i] = 0;
  }
  for (int i = tid; i < 2 * 16 * 72; i += 512) (&xsb[0][0][0])[i] = 0;
  { // x_0
    float xv = x[((size_t)(gid * NCH + wave) * T_SZ) * DD + lane];
    xsb[0][wave][lane] = f2b(xv);
  }

  // ---------------- static weight B-fragments (bf16, gamma-folded) --------
  short8 wf0[2][2], wfA[2][2], wfB[2][2], wfx[2];
#pragma unroll
  for (int n = 0; n < 2; ++n)
#pragma unroll
    for (int j = 0; j < 8; ++j) wfx[n][j] = 0;
#pragma unroll
  for (int s = 0; s < 2; ++s)
#pragma unroll
    for (int n = 0; n < 2; ++n) {
      const int col = p * 32 + n * 16 + m16;
#pragma unroll
      for (int j = 0; j < 8; ++j) {
        const int k = wave * 64 + s * 32 + quad * 8 + j;
        wf0[s][n][j] = (short)f2b(g0v[k] * Wh0[(size_t)k * HH + col]);
        wfA[s][n][j] = (short)f2b(g0v[k] * Wi1[(size_t)k * HH + col]);
        wfB[s][n][j] = (short)f2b(g1v[k] * Wh1[(size_t)k * HH + col]);
      }
    }
  if (wave < 2) {
#pragma unroll
    for (int n = 0; n < 2; ++n) {
      const int col = p * 32 + n * 16 + m16;
#pragma unroll
      for (int j = 0; j < 8; ++j)
        wfx[n][j] = (short)f2b(Wi0[(size_t)(wave * 32 + quad * 8 + j) * HH + col]);
    }
  }

  const int cl   = lane & 31;
  const int ech  = 2 * wave + (lane >> 5);
  const int col_e = p * 32 + cl;
  const float c0f = cvec[col_e],          c0i = cvec[HH + col_e];
  const float c1f = cvec[2 * HH + col_e], c1i = cvec[3 * HH + col_e];
  const float uw0 = cvec[4 * HH + col_e], uw1 = cvec[5 * HH + col_e];
  const float uh1 = cvec[6 * HH + col_e];
  const float g0c = g0v[col_e], be0c = be0v[col_e];
  const float g1c = g1v[col_e], be1c = be1v[col_e];

  float v2prev0 = 0.f, v2prev1 = 0.f;
  __syncthreads();

  for (int t = 0; t < T_SZ; ++t) {
    const int par = t & 1;

    // ================= phase A : L0 MFMAs =================
    {
      f32x4 acc0 = {0.f, 0.f, 0.f, 0.f}, acc1 = {0.f, 0.f, 0.f, 0.f};
#pragma unroll
      for (int s = 0; s < 2; ++s) {
        const short8 af = *(const short8*)&a0bf[m16][wave * 64 + s * 32 + quad * 8];
        acc0 = __builtin_amdgcn_mfma_f32_16x16x32_bf16(af, wf0[s][0], acc0, 0, 0, 0);
        acc1 = __builtin_amdgcn_mfma_f32_16x16x32_bf16(af, wf0[s][1], acc1, 0, 0, 0);
      }
      if (lane < 32) {
#pragma unroll
        for (int r = 0; r < 4; ++r) {
          parts[wave][quad * 4 + r][m16]      = acc0[r];
          parts[wave][quad * 4 + r][16 + m16] = acc1[r];
        }
      }
      if (wave < 2) {
        f32x4 ax0 = {0.f, 0.f, 0.f, 0.f}, ax1 = {0.f, 0.f, 0.f, 0.f};
        const short8 xf = *(const short8*)&xsb[par][m16][wave * 32 + quad * 8];
        ax0 = __builtin_amdgcn_mfma_f32_16x16x32_bf16(xf, wfx[0], ax0, 0, 0, 0);
        ax1 = __builtin_amdgcn_mfma_f32_16x16x32_bf16(xf, wfx[1], ax1, 0, 0, 0);
        if (lane < 32) {
#pragma unroll
          for (int r = 0; r < 4; ++r) {
            partsX[wave][quad * 4 + r][m16]      = ax0[r];
            partsX[wave][quad * 4 + r][16 + m16] = ax1[r];
          }
        }
      }
    }
    __syncthreads();                                    // b1

    // ==== A-epilogue (waves 0-3) | gather v2_1^{t-1} (waves 4-7) ====
    if (wave < 4) {
      float sH = 0.f;
#pragma unroll
      for (int w = 0; w < 8; ++w) sH += parts[w][ech][cl];
      const float sX = partsX[0][ech][cl] + partsX[1][ech][cl];
      float m0p = 0.f, r0p = 0.f;
      if (t > 0) {
        float S = 0.f, Q = 0.f;
#pragma unroll
        for (int i = 0; i < NBLK; ++i) { float2 sq = st0[ech][i]; S += sq.x; Q += sq.y; }
        m0p = S * (1.f / HH);
        r0p = 1.f / sqrtf(Q * (1.f / HH) - m0p * m0p + 1e-5f);
      }
      const float z = ((t == 0) ? c0i : c0f) + r0p * sH - r0p * m0p * uw0 + sX;
      const float h0prev = (t == 0) ? 0.f : (v2prev0 - m0p) * r0p * g0c + be0c;
      const float v2 = tanhf(z) + h0prev;
      v2prev0 = v2;
      const unsigned vb = f2b(v2);
      a0bf[ech][p * 32 + cl] = (unsigned short)vb;
      const unsigned u01 = vb | (__shfl_down(vb, 1) << 16);
      const unsigned u23 = __shfl_down(u01, 2);
      const size_t po = ((((size_t)gslot * 2 + 0) * 2 + par) * NCH + ech) * 8;
      if ((cl & 3) == 0) {
        const ull uu = (ull)u01 | ((ull)u23 << 32);
        stp(payF + po + (cl >> 2), uu);
        st_rlx(payS + po + (cl >> 2), uu);
      }
      float S = v2, Q = v2 * v2;
#pragma unroll
      for (int off = 16; off; off >>= 1) {
        S += __shfl_down(S, off, 32); Q += __shfl_down(Q, off, 32);
      }
      if (cl == 0) {
        st0[ech][p] = make_float2(S, Q);
        const size_t so = (((size_t)gslot * 2 + 0) * 2 + par) * NCH + ech;
        stp(pstF + so, packf2(S, Q));
        st_rlx(pstS + so, packf2(S, Q));
      }
    } else if (t > 0) {
      const bool fastNow = xfast && (*dem == 0);
      if (wave == 4) {
        if (lane < 15) {
          const int pg = gid * NBLK + (lane + (lane >= p));
          bool ok = true;
          if (fastNow) {
            ok = false;
            for (int i2 = 0; i2 < POLL_TO && !ok; ++i2)
              if (ld_l2(flagF + pg * 16 + 8) >= (unsigned)t) ok = true;
            if (!ok) *dem = 1;
          }
          if (!fastNow || !ok)
            while (ld_flag(flagS + pg * 16 + 8) < (unsigned)t) __builtin_amdgcn_s_sleep(1);
        }
        if (lane == 0) *rdy1 = t;
      }
      while (*rdy1 < t) __builtin_amdgcn_s_sleep(1);
      const bool fastP = xfast && (*dem == 0);
      const int par1 = (t - 1) & 1;
      const int base = (wave - 4) * 64 + lane;
#pragma unroll
      for (int it = 0; it < 5; ++it) {
        const int item = base + it * 256;
        if (item < 15 * 72) {
          const int pi = item / 72, rem = item - pi * 72;
          const int pl = pi + (pi >= p);
          const size_t pb = ((size_t)(gid * NBLK + pl) * 2 + 1) * 2 + par1;
          if (rem < 64) {
            const int ch = rem >> 3, j = rem & 7;
            ull u = fastP ? ld_l2_64(payF + (pb * NCH + ch) * 8 + j)
                          : ld_rlx(payS + (pb * NCH + ch) * 8 + j);
            *(ull*)&a1bf[ch][pl * 32 + 4 * j] = u;
          } else {
            const int ch = rem - 64;
            ull u = fastP ? ld_l2_64(pstF + pb * NCH + ch)
                          : ld_rlx(pstS + pb * NCH + ch);
            st1[ch][pl] = make_float2(unpack_lo(u), unpack_hi(u));
          }
        }
      }
    }
    __syncthreads();                                    // b2 (drains publishes)
    if (tid == 0) {
      stp32(flagF + gslot * 16, (unsigned)(t + 1));
      st_flag(flagS + gslot * 16, (unsigned)(t + 1));
    }

    // ================= phase B : Wh1 MFMAs + x prefetch =================
    float xv = 0.f;
    if (t + 1 < T_SZ)
      xv = x[((size_t)(gid * NCH + wave) * T_SZ + (t + 1)) * DD + lane];
    {
      f32x4 acc0 = {0.f, 0.f, 0.f, 0.f}, acc1 = {0.f, 0.f, 0.f, 0.f};
#pragma unroll
      for (int s = 0; s < 2; ++s) {
        const short8 af = *(const short8*)&a1bf[m16][wave * 64 + s * 32 + quad * 8];
        acc0 = __builtin_amdgcn_mfma_f32_16x16x32_bf16(af, wfB[s][0], acc0, 0, 0, 0);
        acc1 = __builtin_amdgcn_mfma_f32_16x16x32_bf16(af, wfB[s][1], acc1, 0, 0, 0);
      }
      if (lane < 32) {
#pragma unroll
        for (int r = 0; r < 4; ++r) {
          partsB[wave][quad * 4 + r][m16]      = acc0[r];
          partsB[wave][quad * 4 + r][16 + m16] = acc1[r];
        }
      }
    }
    if (t + 1 < T_SZ) xsb[(t + 1) & 1][wave][lane] = f2b(xv);

    // -------- gather v2_0^t (the one blocking exchange) --------
    {
      const bool fastNow = xfast && (*dem == 0);
      if (tid < 15) {
        const int pg = gid * NBLK + (tid + (tid >= p));
        bool ok = true;
        if (fastNow) {
          ok = false;
          for (int i2 = 0; i2 < POLL_TO && !ok; ++i2)
            if (ld_l2(flagF + pg * 16) >= (unsigned)(t + 1)) ok = true;
          if (!ok) *dem = 1;
        }
        if (!fastNow || !ok)
          while (ld_flag(flagS + pg * 16) < (unsigned)(t + 1)) __builtin_amdgcn_s_sleep(1);
      }
      if (tid == 0) *rdy0 = t + 1;
      while (*rdy0 < t + 1) __builtin_amdgcn_s_sleep(1);
    }
    {
      const bool fastP = xfast && (*dem == 0);
#pragma unroll
      for (int it = 0; it < 3; ++it) {
        const int item = tid + it * 512;
        if (item < 15 * 72) {
          const int pi = item / 72, rem = item - pi * 72;
          const int pl = pi + (pi >= p);
          const size_t pb = ((size_t)(gid * NBLK + pl) * 2 + 0) * 2 + par;
          if (rem < 64) {
            const int ch = rem >> 3, j = rem & 7;
            ull u = fastP ? ld_l2_64(payF + (pb * NCH + ch) * 8 + j)
                          : ld_rlx(payS + (pb * NCH + ch) * 8 + j);
            *(ull*)&a0bf[ch][pl * 32 + 4 * j] = u;
          } else {
            const int ch = rem - 64;
            ull u = fastP ? ld_l2_64(pstF + pb * NCH + ch)
                          : ld_rlx(pstS + pb * NCH + ch);
            st0[ch][pl] = make_float2(unpack_lo(u), unpack_hi(u));
          }
        }
      }
    }
    __syncthreads();                                    // b3

    // ================= phase C : Wi1 MFMAs =================
    {
      f32x4 acc0 = {0.f, 0.f, 0.f, 0.f}, acc1 = {0.f, 0.f, 0.f, 0.f};
#pragma unroll
      for (int s = 0; s < 2; ++s) {
        const short8 af = *(const short8*)&a0bf[m16][wave * 64 + s * 32 + quad * 8];
        acc0 = __builtin_amdgcn_mfma_f32_16x16x32_bf16(af, wfA[s][0], acc0, 0, 0, 0);
        acc1 = __builtin_amdgcn_mfma_f32_16x16x32_bf16(af, wfA[s][1], acc1, 0, 0, 0);
      }
      if (lane < 32) {
#pragma unroll
        for (int r = 0; r < 4; ++r) {
          parts[wave][quad * 4 + r][m16]      = acc0[r];
          parts[wave][quad * 4 + r][16 + m16] = acc1[r];
        }
      }
    }
    __syncthreads();                                    // b4

    // ============ C-epilogue (waves 0-3) ============
    if (wave < 4) {
      float sB = 0.f, sC = 0.f;
#pragma unroll
      for (int w = 0; w < 8; ++w) { sB += partsB[w][ech][cl]; sC += parts[w][ech][cl]; }
      float S0 = 0.f, Q0 = 0.f;
#pragma unroll
      for (int i = 0; i < NBLK; ++i) { float2 sq = st0[ech][i]; S0 += sq.x; Q0 += sq.y; }
      const float m0 = S0 * (1.f / HH);
      const float r0 = 1.f / sqrtf(Q0 * (1.f / HH) - m0 * m0 + 1e-5f);
      float m1p = 0.f, r1p = 0.f;
      if (t > 0) {
        float S = 0.f, Q = 0.f;
#pragma unroll
        for (int i = 0; i < NBLK; ++i) { float2 sq = st1[ech][i]; S += sq.x; Q += sq.y; }
        m1p = S * (1.f / HH);
        r1p = 1.f / sqrtf(Q * (1.f / HH) - m1p * m1p + 1e-5f);
      }
      const float z = ((t == 0) ? c1i : c1f) + r0 * sC - r0 * m0 * uw1
                      + r1p * sB - r1p * m1p * uh1;
      const float h1prev = (t == 0) ? 0.f : (v2prev1 - m1p) * r1p * g1c + be1c;
      const float v2 = tanhf(z) + h1prev;
      v2prev1 = v2;
      const unsigned vb = f2b(v2);
      a1bf[ech][p * 32 + cl] = (unsigned short)vb;
      const unsigned u01 = vb | (__shfl_down(vb, 1) << 16);
      const unsigned u23 = __shfl_down(u01, 2);
      const size_t po = ((((size_t)gslot * 2 + 1) * 2 + par) * NCH + ech) * 8;
      if ((cl & 3) == 0) {
        const ull uu = (ull)u01 | ((ull)u23 << 32);
        stp(payF + po + (cl >> 2), uu);
        st_rlx(payS + po + (cl >> 2), uu);
      }
      float S = v2, Q = v2 * v2;
#pragma unroll
      for (int off = 16; off; off >>= 1) {
        S += __shfl_down(S, off, 32); Q += __shfl_down(Q, off, 32);
      }
      if (cl == 0) {
        st1[ech][p] = make_float2(S, Q);
        const size_t so = (((size_t)gslot * 2 + 1) * 2 + par) * NCH + ech;
        stp(pstF + so, packf2(S, Q));
        st_rlx(pstS + so, packf2(S, Q));
      }
    }
    __syncthreads();                                    // b5 (drains publishes)
    if (tid == 0) {
      stp32(flagF + gslot * 16 + 8, (unsigned)(t + 1));
      st_flag(flagS + gslot * 16 + 8, (unsigned)(t + 1));
    }
  }

  // ============ head (p==0 blocks): out = LN(v2_1^{T-1}).Wfc + bfc ========
  if (p == 0) {
    {
      const bool fastNow = xfast && (*dem == 0);
      if (tid < 16) {
        const int pg = gid * NBLK + tid;
        bool ok = true;
        if (fastNow) {
          ok = false;
          for (int i2 = 0; i2 < POLL_TO * 16 && !ok; ++i2)
            if (ld_l2(flagF + pg * 16 + 8) >= (unsigned)T_SZ) ok = true;
          if (!ok) *dem = 1;
        }
        if (!fastNow || !ok)
          while (ld_flag(flagS + pg * 16 + 8) < (unsigned)T_SZ) __builtin_amdgcn_s_sleep(1);
      }
    }
    __syncthreads();
    const bool fastP = xfast && (*dem == 0);
    const int c = wave;
    ull su = 0;
    if (lane < 16) {
      const size_t so = (((size_t)(gid * NBLK + lane) * 2 + 1) * 2 + 1) * NCH + c;
      su = fastP ? ld_l2_64(pstF + so) : ld_rlx(pstS + so);
    }
    float S = unpack_lo(su), Q = unpack_hi(su);
#pragma unroll
    for (int off = 32; off; off >>= 1) { S += __shfl_down(S, off); Q += __shfl_down(Q, off); }
    S = __shfl(S, 0); Q = __shfl(Q, 0);
    const float m1 = S * (1.f / HH);
    const float r1 = 1.f / sqrtf(Q * (1.f / HH) - m1 * m1 + 1e-5f);
    float o = 0.f;
#pragma unroll
    for (int it = 0; it < 2; ++it) {
      const int j2 = lane * 2 + it, pl = j2 >> 3, j = j2 & 7;
      const size_t po = ((((size_t)(gid * NBLK + pl) * 2 + 1) * 2 + 1) * NCH + c) * 8 + j;
      ull u = fastP ? ld_l2_64(payF + po) : ld_rlx(payS + po);
#pragma unroll
      for (int q = 0; q < 4; ++q) {
        const int col = pl * 32 + 4 * j + q;
        const float h = (b2f((unsigned short)(u >> (16 * q))) - m1) * r1 * g1v[col] + be1v[col];
        o += h * wfc[col];
      }
    }
#pragma unroll
    for (int off = 32; off; off >>= 1) o += __shfl_down(o, off);
    if (lane == 0) out[gid * NCH + c] = o + bfc[0];
  }
}

extern "C" void kernel_launch(void* const* d_in, const int* in_sizes, int n_in,
                              void* d_out, int out_size, void* d_ws, size_t ws_size,
                              hipStream_t stream) {
  const float* x   = (const float*)d_in[0];
  const float* Wi0 = (const float*)d_in[1];
  const float* bi0 = (const float*)d_in[2];
  const float* Wh0 = (const float*)d_in[3];
  const float* bh0 = (const float*)d_in[4];
  const float* g0  = (const float*)d_in[5];
  const float* be0 = (const float*)d_in[6];
  const float* Wi1 = (const float*)d_in[7];
  const float* bi1 = (const float*)d_in[8];
  const float* Wh1 = (const float*)d_in[9];
  const float* bh1 = (const float*)d_in[10];
  const float* g1  = (const float*)d_in[11];
  const float* be1 = (const float*)d_in[12];
  const float* Wfc = (const float*)d_in[13];
  const float* bfc = (const float*)d_in[14];
  float* out = (float*)d_out;

  // ws: cvec 16K | payF 512K | payS 512K | pstF 64K | pstS 64K
  //     | flagF 16K | flagS 16K | ctrl 4K   (~1.2 MB)
  char* ws = (char*)d_ws;
  float* cvec     = (float*)(ws);
  ull* payF       = (ull*)(ws + 16384);
  ull* payS       = (ull*)(ws + 16384 + 524288);
  ull* pstF       = (ull*)(ws + 16384 + 2 * 524288);
  ull* pstS       = (ull*)(ws + 16384 + 2 * 524288 + 65536);
  unsigned* flagF = (unsigned*)(ws + 16384 + 2 * 524288 + 2 * 65536);
  unsigned* flagS = (unsigned*)(ws + 16384 + 2 * 524288 + 2 * 65536 + 16384);
  unsigned* ctrl  = (unsigned*)(ws + 16384 + 2 * 524288 + 2 * 65536 + 32768);

  prep_kernel<<<256, 256, 0, stream>>>(Wh0, Wi1, Wh1, bi0, bh0, bi1, bh1,
                                       g0, be0, g1, be1, cvec, flagF, flagS, ctrl);
  rnn_mfma<<<256, 512, 0, stream>>>(x, Wi0, Wh0, Wi1, Wh1, cvec,
                                    g0, be0, g1, be1, Wfc, bfc,
                                    payF, payS, pstF, pstS, flagF, flagS, ctrl, out);
}